// Round 2
// baseline (600.251 us; speedup 1.0000x reference)
//
#include <hip/hip_runtime.h>

#define Gg   32
#define Nn   128
#define Hh   128
#define Ee   65536
#define GN   4096      // Gg*Nn
#define GNN  524288    // Gg*Nn*Nn

__device__ __forceinline__ float reluf(float x) { return x > 0.f ? x : 0.f; }

// monotone float <-> u32 key (for atomicMax on floats incl. negatives)
__device__ __forceinline__ unsigned fkey(float f) {
  unsigned u = __float_as_uint(f);
  return (u & 0x80000000u) ? ~u : (u | 0x80000000u);
}
__device__ __forceinline__ float funkey(unsigned k) {
  unsigned u = (k & 0x80000000u) ? (k ^ 0x80000000u) : ~k;
  return __uint_as_float(u);
}

// ---------------- edge_index layout detection ----------------
// int32 layout: e32[i] are real node ids (odd entries ~uniform, nonzero w.h.p.)
// int64 layout: e32[2i+1] are high words == 0 for all i (ids are small positive)
__global__ __launch_bounds__(128) void k_detect(const int* __restrict__ e32,
                                                int* __restrict__ flag) {
  __shared__ int s;
  if (threadIdx.x == 0) s = 0;
  __syncthreads();
  if (e32[2 * threadIdx.x + 1] != 0) atomicOr(&s, 1);
  __syncthreads();
  if (threadIdx.x == 0) *flag = s;  // 1 => int32 layout, 0 => int64 layout
}

// ---------------- encoders ----------------
__global__ __launch_bounds__(256) void k_node_encode(const int* __restrict__ x,
                                                     const float* __restrict__ atom_tab,
                                                     float* __restrict__ nf,
                                                     float* __restrict__ hid) {
  int t = blockIdx.x * 256 + threadIdx.x;      // over GN*Hh
  int v = t >> 7, h = t & 127;
  float s = 0.f;
#pragma unroll
  for (int f = 0; f < 9; ++f) {
    int idx = x[v * 9 + f];
    s += atom_tab[(f * 119 + idx) * Hh + h];
  }
  nf[t] = s;
  hid[t] = 0.f;
}

// all 512 possible bond codes (a0 + 8*a1 + 64*a2)
__global__ __launch_bounds__(256) void k_bond_fts(const float* __restrict__ bond_tab,
                                                  float* __restrict__ bf) {
  int t = blockIdx.x * 256 + threadIdx.x;      // 512*128
  int c = t >> 7, h = t & 127;
  int a0 = c & 7, a1 = (c >> 3) & 7, a2 = (c >> 6) & 7;
  bf[t] = bond_tab[(0 * 8 + a0) * Hh + h] + bond_tab[(1 * 8 + a1) * Hh + h] +
          bond_tab[(2 * 8 + a2) * Hh + h];
}

// ---------------- edge winner (last-edge-wins == max edge id) ----------------
__global__ __launch_bounds__(256) void k_scatter_win(const int* __restrict__ e32,
                                                     const int* __restrict__ flag,
                                                     int* __restrict__ win) {
  int e = blockIdx.x * 256 + threadIdx.x;
  int sg, dg;
  if (*flag) {               // int32 layout
    sg = e32[e];
    dg = e32[Ee + e];
  } else {                   // int64 layout: low words at even offsets
    sg = e32[2 * e];
    dg = e32[2 * Ee + 2 * e];
  }
  int g = sg / Nn;
  int s = sg % Nn;
  int d = dg % Nn;
  atomicMax(&win[(g * Nn + s) * Nn + d], e);
}

__global__ __launch_bounds__(256) void k_collect(const int* __restrict__ win,
                                                 const int* __restrict__ eattr,
                                                 unsigned* __restrict__ recs,
                                                 int* __restrict__ cnt) {
  int idx = blockIdx.x * 256 + threadIdx.x;    // over GNN
  int e = win[idx];
  if (e < 0) return;
  int a0 = eattr[e * 3 + 0], a1 = eattr[e * 3 + 1], a2 = eattr[e * 3 + 2];
  int code = a0 + (a1 << 3) + (a2 << 6);
  int p = atomicAdd(cnt, 1);
  recs[p] = ((unsigned)idx << 9) | (unsigned)code;
}

// ---------------- per-layer small table: me_tab[c] = bf[c]@W_me + b_me + b_mg ----
__global__ __launch_bounds__(128) void k_me_tab(const float* __restrict__ bf,
                                                const float* __restrict__ W_me,
                                                const float* __restrict__ b_me,
                                                const float* __restrict__ b_mg,
                                                float* __restrict__ me) {
  __shared__ float v[Hh];
  int c = blockIdx.x, j = threadIdx.x;
  v[j] = bf[c * Hh + j];
  __syncthreads();
  float acc = b_me[j] + b_mg[j];
  for (int i = 0; i < Hh; ++i) acc += v[i] * W_me[i * Hh + j];
  me[c * Hh + j] = acc;
}

__global__ __launch_bounds__(256) void k_init_agg(unsigned* __restrict__ aggk) {
  int t = blockIdx.x * 256 + threadIdx.x;
  aggk[t] = fkey(-1.0e9f);
}

// ---------------- m1,m2 = [nf|hid] @ W_m1 / W_m2  (16-node tiles) ----------------
__global__ __launch_bounds__(256) void k_m12(const float* __restrict__ nf,
                                             const float* __restrict__ hid,
                                             const float* __restrict__ W1,
                                             const float* __restrict__ bi1,
                                             const float* __restrict__ W2,
                                             const float* __restrict__ bi2,
                                             float* __restrict__ m1,
                                             float* __restrict__ m2) {
  __shared__ float As[16][256];
  __shared__ float Wt1[16][128];
  __shared__ float Wt2[16][128];
  int tid = threadIdx.x;
  int v0 = blockIdx.x * 16;
#pragma unroll
  for (int i = 0; i < 16; ++i) {
    int e = tid + i * 256;
    int row = e >> 8, col = e & 255;
    As[row][col] = (col < 128) ? nf[(v0 + row) * Hh + col]
                               : hid[(v0 + row) * Hh + (col - 128)];
  }
  float a1[2][4], a2[2][4];
#pragma unroll
  for (int i = 0; i < 2; ++i)
#pragma unroll
    for (int j = 0; j < 4; ++j) { a1[i][j] = 0.f; a2[i][j] = 0.f; }
  int c0 = tid & 31, r0 = tid >> 5;  // rows r0, r0+8 ; cols c0+32j
  for (int k0 = 0; k0 < 256; k0 += 16) {
    __syncthreads();
#pragma unroll
    for (int i = 0; i < 8; ++i) {
      int e = tid + i * 256;
      int rr = e >> 7, cc = e & 127;
      Wt1[rr][cc] = W1[(k0 + rr) * Hh + cc];
      Wt2[rr][cc] = W2[(k0 + rr) * Hh + cc];
    }
    __syncthreads();
#pragma unroll
    for (int kk = 0; kk < 16; ++kk) {
      float a[2] = {As[r0][k0 + kk], As[r0 + 8][k0 + kk]};
      float w1[4], w2[4];
#pragma unroll
      for (int j = 0; j < 4; ++j) { w1[j] = Wt1[kk][c0 + 32 * j]; w2[j] = Wt2[kk][c0 + 32 * j]; }
#pragma unroll
      for (int i = 0; i < 2; ++i)
#pragma unroll
        for (int j = 0; j < 4; ++j) { a1[i][j] += a[i] * w1[j]; a2[i][j] += a[i] * w2[j]; }
    }
  }
#pragma unroll
  for (int i = 0; i < 2; ++i)
#pragma unroll
    for (int j = 0; j < 4; ++j) {
      int r = v0 + r0 + 8 * i, c = c0 + 32 * j;
      m1[r * Hh + c] = a1[i][j] + bi1[c];
      m2[r * Hh + c] = a2[i][j] + bi2[c];
    }
}

// ---------------- edge phase: gather -> relu -> @W_h1 -> relu -> @W_h2 -> max-scatter
__global__ __launch_bounds__(256) void k_edge(const unsigned* __restrict__ recs,
                                              const int* __restrict__ cnt,
                                              const float* __restrict__ m1,
                                              const float* __restrict__ m2,
                                              const float* __restrict__ me,
                                              const float* __restrict__ W_h1,
                                              const float* __restrict__ b_h1,
                                              const float* __restrict__ W_h2,
                                              const float* __restrict__ b_h2,
                                              unsigned* __restrict__ aggk) {
  __shared__ unsigned srec[64];
  __shared__ float Ms[64][128];
  __shared__ float Ts[64][128];
  __shared__ float Wt[16][128];
  int tid = threadIdx.x;
  int base = blockIdx.x * 64;
  int n = *cnt;
  if (tid < 64) {
    int r = base + tid;
    srec[tid] = (r < n) ? recs[r] : 0xFFFFFFFFu;
  }
  __syncthreads();
  // build M tile
  {
    int c = tid & 127, rr = tid >> 7;
#pragma unroll
    for (int i = 0; i < 32; ++i) {
      int r = rr + i * 2;
      unsigned rec = srec[r];
      float v = 0.f;
      if (rec != 0xFFFFFFFFu) {
        int code = rec & 511;
        int idx = (int)(rec >> 9);
        int d = idx & 127, s = (idx >> 7) & 127, g = idx >> 14;
        float a = m1[((g << 7) + d) * Hh + c] + m2[((g << 7) + s) * Hh + c] +
                  me[code * Hh + c];
        v = reluf(a);
      }
      Ms[r][c] = v;
    }
  }
  int c0 = tid & 31, r0 = tid >> 5;  // rows r0+8i (i<8), cols c0+32j (j<4)
  float acc[8][4];
#pragma unroll
  for (int i = 0; i < 8; ++i)
#pragma unroll
    for (int j = 0; j < 4; ++j) acc[i][j] = 0.f;
  // GEMM1
  for (int k0 = 0; k0 < 128; k0 += 16) {
    __syncthreads();
#pragma unroll
    for (int i = 0; i < 8; ++i) {
      int e = tid + i * 256;
      Wt[e >> 7][e & 127] = W_h1[(k0 + (e >> 7)) * Hh + (e & 127)];
    }
    __syncthreads();
#pragma unroll
    for (int kk = 0; kk < 16; ++kk) {
      float w[4], a[8];
#pragma unroll
      for (int j = 0; j < 4; ++j) w[j] = Wt[kk][c0 + 32 * j];
#pragma unroll
      for (int i = 0; i < 8; ++i) a[i] = Ms[r0 + 8 * i][k0 + kk];
#pragma unroll
      for (int i = 0; i < 8; ++i)
#pragma unroll
        for (int j = 0; j < 4; ++j) acc[i][j] += a[i] * w[j];
    }
  }
  __syncthreads();
#pragma unroll
  for (int i = 0; i < 8; ++i)
#pragma unroll
    for (int j = 0; j < 4; ++j)
      Ts[r0 + 8 * i][c0 + 32 * j] = reluf(acc[i][j] + b_h1[c0 + 32 * j]);
  // GEMM2
#pragma unroll
  for (int i = 0; i < 8; ++i)
#pragma unroll
    for (int j = 0; j < 4; ++j) acc[i][j] = 0.f;
  for (int k0 = 0; k0 < 128; k0 += 16) {
    __syncthreads();
#pragma unroll
    for (int i = 0; i < 8; ++i) {
      int e = tid + i * 256;
      Wt[e >> 7][e & 127] = W_h2[(k0 + (e >> 7)) * Hh + (e & 127)];
    }
    __syncthreads();
#pragma unroll
    for (int kk = 0; kk < 16; ++kk) {
      float w[4], a[8];
#pragma unroll
      for (int j = 0; j < 4; ++j) w[j] = Wt[kk][c0 + 32 * j];
#pragma unroll
      for (int i = 0; i < 8; ++i) a[i] = Ts[r0 + 8 * i][k0 + kk];
#pragma unroll
      for (int i = 0; i < 8; ++i)
#pragma unroll
        for (int j = 0; j < 4; ++j) acc[i][j] += a[i] * w[j];
    }
  }
  // scatter max into agg
#pragma unroll
  for (int i = 0; i < 8; ++i) {
    unsigned rec = srec[r0 + 8 * i];
    if (rec == 0xFFFFFFFFu) continue;
    int idx = (int)(rec >> 9);
    int d = idx & 127, g = idx >> 14;
    unsigned* dst = aggk + ((g << 7) + d) * Hh;
#pragma unroll
    for (int j = 0; j < 4; ++j) {
      float u = acc[i][j] + b_h2[c0 + 32 * j];
      atomicMax(dst + c0 + 32 * j, fkey(u));
    }
  }
}

// ---------------- hid update: relu([nf|hid|agg] @ [Wo1;Wo2] + biases) ----------------
__global__ __launch_bounds__(256) void k_out(const float* __restrict__ nf,
                                             const float* __restrict__ hid,
                                             const unsigned* __restrict__ aggk,
                                             const float* __restrict__ Wo1,
                                             const float* __restrict__ bo1,
                                             const float* __restrict__ Wo2,
                                             const float* __restrict__ bo2,
                                             float* __restrict__ hidn) {
  __shared__ float As[16][384];
  __shared__ float Wt[16][128];
  int tid = threadIdx.x;
  int v0 = blockIdx.x * 16;
#pragma unroll
  for (int seg = 0; seg < 3; ++seg) {
#pragma unroll
    for (int i = 0; i < 8; ++i) {
      int e = tid + i * 256;
      int row = e >> 7, col = e & 127;
      float val;
      if (seg == 0) val = nf[(v0 + row) * Hh + col];
      else if (seg == 1) val = hid[(v0 + row) * Hh + col];
      else val = funkey(aggk[(v0 + row) * Hh + col]);
      As[row][seg * 128 + col] = val;
    }
  }
  float acc[2][4];
#pragma unroll
  for (int i = 0; i < 2; ++i)
#pragma unroll
    for (int j = 0; j < 4; ++j) acc[i][j] = 0.f;
  int c0 = tid & 31, r0 = tid >> 5;
  for (int k0 = 0; k0 < 384; k0 += 16) {
    __syncthreads();
#pragma unroll
    for (int i = 0; i < 8; ++i) {
      int e = tid + i * 256;
      int rr = e >> 7, cc = e & 127;
      int k = k0 + rr;
      Wt[rr][cc] = (k < 256) ? Wo1[k * Hh + cc] : Wo2[(k - 256) * Hh + cc];
    }
    __syncthreads();
#pragma unroll
    for (int kk = 0; kk < 16; ++kk) {
      float a[2] = {As[r0][k0 + kk], As[r0 + 8][k0 + kk]};
      float w[4];
#pragma unroll
      for (int j = 0; j < 4; ++j) w[j] = Wt[kk][c0 + 32 * j];
#pragma unroll
      for (int i = 0; i < 2; ++i)
#pragma unroll
        for (int j = 0; j < 4; ++j) acc[i][j] += a[i] * w[j];
    }
  }
#pragma unroll
  for (int i = 0; i < 2; ++i)
#pragma unroll
    for (int j = 0; j < 4; ++j) {
      int r = v0 + r0 + 8 * i, c = c0 + 32 * j;
      hidn[r * Hh + c] = reluf(acc[i][j] + bo1[c] + bo2[c]);
    }
}

// ---------------- readout head ----------------
__global__ __launch_bounds__(128) void k_head(const float* __restrict__ hid,
                                              const float* __restrict__ Wg1,
                                              const float* __restrict__ bg1,
                                              const float* __restrict__ Wg2,
                                              const float* __restrict__ bg2,
                                              float* __restrict__ out) {
  __shared__ float emb[Hh];
  __shared__ float tt[Hh];
  int g = blockIdx.x, j = threadIdx.x;
  float s = 0.f;
  for (int n = 0; n < Nn; ++n) s += hid[(g * Nn + n) * Hh + j];
  emb[j] = s * (1.f / Nn);
  __syncthreads();
  float a = bg1[j];
  for (int i = 0; i < Hh; ++i) a += emb[i] * Wg1[i * Hh + j];
  tt[j] = reluf(a);
  __syncthreads();
  if (j < 12) {
    float o = bg2[j];
    for (int i = 0; i < Hh; ++i) o += tt[i] * Wg2[i * 12 + j];
    out[g * 12 + j] = o;
  }
}

extern "C" void kernel_launch(void* const* d_in, const int* in_sizes, int n_in,
                              void* d_out, int out_size, void* d_ws, size_t ws_size,
                              hipStream_t stream) {
  const int* x = (const int*)d_in[0];
  const int* eidx32 = (const int*)d_in[1];
  const int* eattr = (const int*)d_in[2];
  const float* atom_tab = (const float*)d_in[4];
  const float* bond_tab = (const float*)d_in[5];
  const float* W_m1 = (const float*)d_in[6];
  const float* b_m1 = (const float*)d_in[7];
  const float* W_m2 = (const float*)d_in[8];
  const float* b_m2 = (const float*)d_in[9];
  const float* W_me = (const float*)d_in[10];
  const float* b_me = (const float*)d_in[11];
  const float* b_mg = (const float*)d_in[13];
  const float* W_h1 = (const float*)d_in[14];
  const float* b_h1 = (const float*)d_in[15];
  const float* W_h2 = (const float*)d_in[16];
  const float* b_h2 = (const float*)d_in[17];
  const float* W_o1 = (const float*)d_in[18];
  const float* b_o1 = (const float*)d_in[19];
  const float* W_o2 = (const float*)d_in[20];
  const float* b_o2 = (const float*)d_in[21];
  const float* Wg1 = (const float*)d_in[22];
  const float* bg1 = (const float*)d_in[23];
  const float* Wg2 = (const float*)d_in[24];
  const float* bg2 = (const float*)d_in[25];
  float* out = (float*)d_out;

  char* ws = (char*)d_ws;
  float* nf = (float*)(ws);                                 // 2MB
  float* hidA = (float*)(ws + (2u << 20));                  // 2MB
  float* hidB = (float*)(ws + (4u << 20));                  // 2MB
  float* m1 = (float*)(ws + (6u << 20));                    // 2MB
  float* m2 = (float*)(ws + (8u << 20));                    // 2MB
  unsigned* aggk = (unsigned*)(ws + (10u << 20));           // 2MB
  int* win = (int*)(ws + (12u << 20));                      // 2MB
  float* bf = (float*)(ws + (14u << 20));                   // 256KB
  float* me = (float*)(ws + (14u << 20) + (256u << 10));    // 256KB
  unsigned* recs = (unsigned*)(ws + (14u << 20) + (512u << 10));  // 256KB
  int* cnt = (int*)(ws + (14u << 20) + (768u << 10));       // 4B
  int* eflag = cnt + 1;                                     // 4B

  hipMemsetAsync(win, 0xFF, GNN * sizeof(int), stream);
  hipMemsetAsync(cnt, 0, sizeof(int), stream);
  k_detect<<<1, 128, 0, stream>>>(eidx32, eflag);
  k_node_encode<<<2048, 256, 0, stream>>>(x, atom_tab, nf, hidA);
  k_bond_fts<<<256, 256, 0, stream>>>(bond_tab, bf);
  k_scatter_win<<<256, 256, 0, stream>>>(eidx32, eflag, win);
  k_collect<<<2048, 256, 0, stream>>>(win, eattr, recs, cnt);

  float* hc = hidA;
  float* hn = hidB;
  for (int l = 0; l < 2; ++l) {
    k_me_tab<<<512, 128, 0, stream>>>(bf, W_me + l * Hh * Hh, b_me + l * Hh,
                                      b_mg + l * Hh, me);
    k_m12<<<256, 256, 0, stream>>>(nf, hc, W_m1 + l * 2 * Hh * Hh, b_m1 + l * Hh,
                                   W_m2 + l * 2 * Hh * Hh, b_m2 + l * Hh, m1, m2);
    k_init_agg<<<2048, 256, 0, stream>>>(aggk);
    k_edge<<<1024, 256, 0, stream>>>(recs, cnt, m1, m2, me, W_h1 + l * Hh * Hh,
                                     b_h1 + l * Hh, W_h2 + l * Hh * Hh,
                                     b_h2 + l * Hh, aggk);
    k_out<<<256, 256, 0, stream>>>(nf, hc, aggk, W_o1 + l * 2 * Hh * Hh,
                                   b_o1 + l * Hh, W_o2 + l * Hh * Hh, b_o2 + l * Hh,
                                   hn);
    float* t = hc; hc = hn; hn = t;
  }
  k_head<<<32, 128, 0, stream>>>(hc, Wg1, bg1, Wg2, bg2, out);
}

// Round 3
// 497.223 us; speedup vs baseline: 1.2072x; 1.2072x over previous
//
#include <hip/hip_runtime.h>

#define Gg   32
#define Nn   128
#define Hh   128
#define Ee   65536
#define GN   4096      // Gg*Nn
#define GNN  524288    // Gg*Nn*Nn

typedef unsigned short ushort_t;
typedef __attribute__((ext_vector_type(8))) __bf16 bf16x8;
typedef __attribute__((ext_vector_type(4))) float f32x4;

__device__ __forceinline__ float reluf(float x) { return x > 0.f ? x : 0.f; }

// monotone float <-> u32 key (for atomicMax on floats incl. negatives)
__device__ __forceinline__ unsigned fkey(float f) {
  unsigned u = __float_as_uint(f);
  return (u & 0x80000000u) ? ~u : (u | 0x80000000u);
}
__device__ __forceinline__ float funkey(unsigned k) {
  unsigned u = (k & 0x80000000u) ? (k ^ 0x80000000u) : ~k;
  return __uint_as_float(u);
}

// round-to-nearest-even f32 -> bf16 bits
__device__ __forceinline__ ushort_t bfh(float x) {
  unsigned u = __float_as_uint(x);
  return (ushort_t)((u + 0x7FFFu + ((u >> 16) & 1u)) >> 16);
}
__device__ __forceinline__ void split2(float x, ushort_t& h, ushort_t& l) {
  h = bfh(x);
  float hf = __uint_as_float(((unsigned)h) << 16);
  l = bfh(x - hf);
}

// ---------------- edge_index layout detection ----------------
__global__ __launch_bounds__(128) void k_detect(const int* __restrict__ e32,
                                                int* __restrict__ flag) {
  __shared__ int s;
  if (threadIdx.x == 0) s = 0;
  __syncthreads();
  if (e32[2 * threadIdx.x + 1] != 0) atomicOr(&s, 1);
  __syncthreads();
  if (threadIdx.x == 0) *flag = s;  // 1 => int32 layout, 0 => int64 layout
}

// ---------------- encoders ----------------
__global__ __launch_bounds__(256) void k_node_encode(const int* __restrict__ x,
                                                     const float* __restrict__ atom_tab,
                                                     float* __restrict__ nf,
                                                     float* __restrict__ hid) {
  int t = blockIdx.x * 256 + threadIdx.x;      // over GN*Hh
  int v = t >> 7, h = t & 127;
  float s = 0.f;
#pragma unroll
  for (int f = 0; f < 9; ++f) {
    int idx = x[v * 9 + f];
    s += atom_tab[(f * 119 + idx) * Hh + h];
  }
  nf[t] = s;
  hid[t] = 0.f;
}

__global__ __launch_bounds__(256) void k_bond_fts(const float* __restrict__ bond_tab,
                                                  float* __restrict__ bf) {
  int t = blockIdx.x * 256 + threadIdx.x;      // 512*128
  int c = t >> 7, h = t & 127;
  int a0 = c & 7, a1 = (c >> 3) & 7, a2 = (c >> 6) & 7;
  bf[t] = bond_tab[(0 * 8 + a0) * Hh + h] + bond_tab[(1 * 8 + a1) * Hh + h] +
          bond_tab[(2 * 8 + a2) * Hh + h];
}

// ---------------- edge winner (last-edge-wins == max edge id) ----------------
__global__ __launch_bounds__(256) void k_scatter_win(const int* __restrict__ e32,
                                                     const int* __restrict__ flag,
                                                     int* __restrict__ win) {
  int e = blockIdx.x * 256 + threadIdx.x;
  int sg, dg;
  if (*flag) { sg = e32[e]; dg = e32[Ee + e]; }
  else       { sg = e32[2 * e]; dg = e32[2 * Ee + 2 * e]; }
  int g = sg / Nn;
  int s = sg % Nn;
  int d = dg % Nn;
  atomicMax(&win[(g * Nn + s) * Nn + d], e);
}

__global__ __launch_bounds__(256) void k_collect(const int* __restrict__ win,
                                                 const int* __restrict__ eattr,
                                                 unsigned* __restrict__ recs,
                                                 int* __restrict__ cnt) {
  int idx = blockIdx.x * 256 + threadIdx.x;    // over GNN
  int e = win[idx];
  if (e < 0) return;
  int a0 = eattr[e * 3 + 0], a1 = eattr[e * 3 + 1], a2 = eattr[e * 3 + 2];
  int code = a0 + (a1 << 3) + (a2 << 6);
  int p = atomicAdd(cnt, 1);
  recs[p] = ((unsigned)idx << 9) | (unsigned)code;
}

// ---------------- weight prep: W_h1/W_h2 -> transposed hi/lo bf16 ----------------
// wt layout: [layer(2)][mat(2)][part(2)][n(128)][k(128)] ushort
__global__ __launch_bounds__(256) void k_wprep(const float* __restrict__ W_h1,
                                               const float* __restrict__ W_h2,
                                               ushort_t* __restrict__ wt) {
  int t = blockIdx.x * 256 + threadIdx.x;      // 2*2*16384
  int l = t >> 15;
  int m = (t >> 14) & 1;
  int e = t & 16383;
  int n = e & 127, k = e >> 7;
  const float* W = (m == 0 ? W_h1 : W_h2) + l * 16384;
  float v = W[k * 128 + n];
  ushort_t h, lo;
  split2(v, h, lo);
  int base = ((l * 2 + m) * 2) * 16384;
  wt[base + n * 128 + k] = h;
  wt[base + 16384 + n * 128 + k] = lo;
}

// ---------------- me table + agg init (fused) ----------------
__global__ __launch_bounds__(256) void k_me_init(const float* __restrict__ bf,
                                                 const float* __restrict__ W_me,
                                                 const float* __restrict__ b_me,
                                                 const float* __restrict__ b_mg,
                                                 float* __restrict__ me,
                                                 unsigned* __restrict__ aggk) {
  __shared__ float v[2][128];
  int tid = threadIdx.x;
  int half = tid >> 7, j = tid & 127;
  int c = blockIdx.x * 2 + half;
  v[half][j] = bf[c * 128 + j];
  __syncthreads();
  float acc = b_me[j] + b_mg[j];
  for (int i = 0; i < 128; ++i) acc += v[half][i] * W_me[i * 128 + j];
  me[c * 128 + j] = acc;
  unsigned key = fkey(-1.0e9f);
#pragma unroll
  for (int i = 0; i < 8; ++i) aggk[blockIdx.x * 2048 + i * 256 + tid] = key;
}

// ---------------- m1,m2 = [nf|hid] @ W_m1 / W_m2 ----------------
__global__ __launch_bounds__(256) void k_m12(const float* __restrict__ nf,
                                             const float* __restrict__ hid,
                                             const float* __restrict__ W1,
                                             const float* __restrict__ bi1,
                                             const float* __restrict__ W2,
                                             const float* __restrict__ bi2,
                                             float* __restrict__ m1,
                                             float* __restrict__ m2) {
  __shared__ float As[16][256];
  __shared__ float Wt1[16][128];
  __shared__ float Wt2[16][128];
  int tid = threadIdx.x;
  int v0 = blockIdx.x * 16;
#pragma unroll
  for (int i = 0; i < 16; ++i) {
    int e = tid + i * 256;
    int row = e >> 8, col = e & 255;
    As[row][col] = (col < 128) ? nf[(v0 + row) * Hh + col]
                               : hid[(v0 + row) * Hh + (col - 128)];
  }
  float a1[2][4], a2[2][4];
#pragma unroll
  for (int i = 0; i < 2; ++i)
#pragma unroll
    for (int j = 0; j < 4; ++j) { a1[i][j] = 0.f; a2[i][j] = 0.f; }
  int c0 = tid & 31, r0 = tid >> 5;
  for (int k0 = 0; k0 < 256; k0 += 16) {
    __syncthreads();
#pragma unroll
    for (int i = 0; i < 8; ++i) {
      int e = tid + i * 256;
      int rr = e >> 7, cc = e & 127;
      Wt1[rr][cc] = W1[(k0 + rr) * Hh + cc];
      Wt2[rr][cc] = W2[(k0 + rr) * Hh + cc];
    }
    __syncthreads();
#pragma unroll
    for (int kk = 0; kk < 16; ++kk) {
      float a[2] = {As[r0][k0 + kk], As[r0 + 8][k0 + kk]};
      float w1[4], w2[4];
#pragma unroll
      for (int j = 0; j < 4; ++j) { w1[j] = Wt1[kk][c0 + 32 * j]; w2[j] = Wt2[kk][c0 + 32 * j]; }
#pragma unroll
      for (int i = 0; i < 2; ++i)
#pragma unroll
        for (int j = 0; j < 4; ++j) { a1[i][j] += a[i] * w1[j]; a2[i][j] += a[i] * w2[j]; }
    }
  }
#pragma unroll
  for (int i = 0; i < 2; ++i)
#pragma unroll
    for (int j = 0; j < 4; ++j) {
      int r = v0 + r0 + 8 * i, c = c0 + 32 * j;
      m1[r * Hh + c] = a1[i][j] + bi1[c];
      m2[r * Hh + c] = a2[i][j] + bi2[c];
    }
}

// ---------------- MFMA helpers ----------------
__device__ __forceinline__ void load_afrag(const ushort_t (*MH)[136],
                                           const ushort_t (*ML)[136],
                                           int row, int lg,
                                           bf16x8 ah[4], bf16x8 al[4]) {
#pragma unroll
  for (int kf = 0; kf < 4; ++kf) {
    ah[kf] = *(const bf16x8*)&MH[row][lg * 8 + 32 * kf];
    al[kf] = *(const bf16x8*)&ML[row][lg * 8 + 32 * kf];
  }
}

__device__ __forceinline__ void wave_gemm(const ushort_t* __restrict__ wth,
                                          const ushort_t* __restrict__ wtl,
                                          const bf16x8 ah[4], const bf16x8 al[4],
                                          int lr, int lg, f32x4 acc[8]) {
#pragma unroll
  for (int nf = 0; nf < 8; ++nf) {
    acc[nf] = (f32x4){0.f, 0.f, 0.f, 0.f};
    const ushort_t* bh_base = wth + (16 * nf + lr) * 128 + lg * 8;
    const ushort_t* bl_base = wtl + (16 * nf + lr) * 128 + lg * 8;
#pragma unroll
    for (int kf = 0; kf < 4; ++kf) {
      bf16x8 bh = *(const bf16x8*)(bh_base + 32 * kf);
      bf16x8 bl = *(const bf16x8*)(bl_base + 32 * kf);
      acc[nf] = __builtin_amdgcn_mfma_f32_16x16x32_bf16(ah[kf], bh, acc[nf], 0, 0, 0);
      acc[nf] = __builtin_amdgcn_mfma_f32_16x16x32_bf16(ah[kf], bl, acc[nf], 0, 0, 0);
      acc[nf] = __builtin_amdgcn_mfma_f32_16x16x32_bf16(al[kf], bh, acc[nf], 0, 0, 0);
    }
  }
}

// ---------------- edge phase (MFMA bf16x3) ----------------
__global__ __launch_bounds__(256) void k_edge(const unsigned* __restrict__ recs,
                                              const int* __restrict__ cnt,
                                              const float* __restrict__ m1,
                                              const float* __restrict__ m2,
                                              const float* __restrict__ me,
                                              const ushort_t* __restrict__ wt1h,
                                              const ushort_t* __restrict__ wt1l,
                                              const ushort_t* __restrict__ wt2h,
                                              const ushort_t* __restrict__ wt2l,
                                              const float* __restrict__ b_h1,
                                              const float* __restrict__ b_h2,
                                              unsigned* __restrict__ aggk) {
  __shared__ ushort_t MH[64][136];
  __shared__ ushort_t ML[64][136];
  __shared__ unsigned srec[64];
  int tid = threadIdx.x;
  int n = *cnt;
  if (tid < 64) {
    int r = blockIdx.x * 64 + tid;
    srec[tid] = (r < n) ? recs[r] : 0xFFFFFFFFu;
  }
  __syncthreads();
  // build M tile (hi/lo bf16)
  {
    int c = tid & 127, rr = tid >> 7;
#pragma unroll
    for (int i = 0; i < 32; ++i) {
      int r = rr + i * 2;
      unsigned rec = srec[r];
      float v = 0.f;
      if (rec != 0xFFFFFFFFu) {
        int code = rec & 511;
        unsigned idx = rec >> 9;
        int d = idx & 127, s = (idx >> 7) & 127, g = idx >> 14;
        v = reluf(m1[((g << 7) + d) * Hh + c] + m2[((g << 7) + s) * Hh + c] +
                  me[code * Hh + c]);
      }
      ushort_t h, l;
      split2(v, h, l);
      MH[r][c] = h;
      ML[r][c] = l;
    }
  }
  __syncthreads();

  int lane = tid & 63, wid = tid >> 6;
  int lr = lane & 15, lg = lane >> 4;
  float b1v[8], b2v[8];
#pragma unroll
  for (int nf = 0; nf < 8; ++nf) {
    b1v[nf] = b_h1[16 * nf + lr];
    b2v[nf] = b_h2[16 * nf + lr];
  }
  int arow = 16 * wid + lr;
  bf16x8 ah[4], al[4];
  load_afrag(MH, ML, arow, lg, ah, al);
  f32x4 acc[8];
  wave_gemm(wt1h, wt1l, ah, al, lr, lg, acc);
  // T = relu(acc + b1) -> back into MH/ML (wave-private rows)
#pragma unroll
  for (int nf = 0; nf < 8; ++nf)
#pragma unroll
    for (int reg = 0; reg < 4; ++reg) {
      float t = reluf(acc[nf][reg] + b1v[nf]);
      int row = 16 * wid + lg * 4 + reg;
      int col = 16 * nf + lr;
      ushort_t h, l;
      split2(t, h, l);
      MH[row][col] = h;
      ML[row][col] = l;
    }
  __syncthreads();
  load_afrag(MH, ML, arow, lg, ah, al);
  wave_gemm(wt2h, wt2l, ah, al, lr, lg, acc);
  // scatter max into agg
#pragma unroll
  for (int reg = 0; reg < 4; ++reg) {
    int row = 16 * wid + lg * 4 + reg;
    unsigned rec = srec[row];
    if (rec == 0xFFFFFFFFu) continue;
    unsigned idx = rec >> 9;
    int d = idx & 127, g = idx >> 14;
    unsigned* dst = aggk + (((g << 7) + d) << 7);
#pragma unroll
    for (int nf = 0; nf < 8; ++nf)
      atomicMax(dst + 16 * nf + lr, fkey(acc[nf][reg] + b2v[nf]));
  }
}

// ---------------- hid update ----------------
__global__ __launch_bounds__(256) void k_out(const float* __restrict__ nf,
                                             const float* __restrict__ hid,
                                             const unsigned* __restrict__ aggk,
                                             const float* __restrict__ Wo1,
                                             const float* __restrict__ bo1,
                                             const float* __restrict__ Wo2,
                                             const float* __restrict__ bo2,
                                             float* __restrict__ hidn) {
  __shared__ float As[16][384];
  __shared__ float Wt[16][128];
  int tid = threadIdx.x;
  int v0 = blockIdx.x * 16;
#pragma unroll
  for (int seg = 0; seg < 3; ++seg) {
#pragma unroll
    for (int i = 0; i < 8; ++i) {
      int e = tid + i * 256;
      int row = e >> 7, col = e & 127;
      float val;
      if (seg == 0) val = nf[(v0 + row) * Hh + col];
      else if (seg == 1) val = hid[(v0 + row) * Hh + col];
      else val = funkey(aggk[(v0 + row) * Hh + col]);
      As[row][seg * 128 + col] = val;
    }
  }
  float acc[2][4];
#pragma unroll
  for (int i = 0; i < 2; ++i)
#pragma unroll
    for (int j = 0; j < 4; ++j) acc[i][j] = 0.f;
  int c0 = tid & 31, r0 = tid >> 5;
  for (int k0 = 0; k0 < 384; k0 += 16) {
    __syncthreads();
#pragma unroll
    for (int i = 0; i < 8; ++i) {
      int e = tid + i * 256;
      int rr = e >> 7, cc = e & 127;
      int k = k0 + rr;
      Wt[rr][cc] = (k < 256) ? Wo1[k * Hh + cc] : Wo2[(k - 256) * Hh + cc];
    }
    __syncthreads();
#pragma unroll
    for (int kk = 0; kk < 16; ++kk) {
      float a[2] = {As[r0][k0 + kk], As[r0 + 8][k0 + kk]};
      float w[4];
#pragma unroll
      for (int j = 0; j < 4; ++j) w[j] = Wt[kk][c0 + 32 * j];
#pragma unroll
      for (int i = 0; i < 2; ++i)
#pragma unroll
        for (int j = 0; j < 4; ++j) acc[i][j] += a[i] * w[j];
    }
  }
#pragma unroll
  for (int i = 0; i < 2; ++i)
#pragma unroll
    for (int j = 0; j < 4; ++j) {
      int r = v0 + r0 + 8 * i, c = c0 + 32 * j;
      hidn[r * Hh + c] = reluf(acc[i][j] + bo1[c] + bo2[c]);
    }
}

// ---------------- readout head ----------------
__global__ __launch_bounds__(128) void k_head(const float* __restrict__ hid,
                                              const float* __restrict__ Wg1,
                                              const float* __restrict__ bg1,
                                              const float* __restrict__ Wg2,
                                              const float* __restrict__ bg2,
                                              float* __restrict__ out) {
  __shared__ float emb[Hh];
  __shared__ float tt[Hh];
  int g = blockIdx.x, j = threadIdx.x;
  float s = 0.f;
  for (int n = 0; n < Nn; ++n) s += hid[(g * Nn + n) * Hh + j];
  emb[j] = s * (1.f / Nn);
  __syncthreads();
  float a = bg1[j];
  for (int i = 0; i < Hh; ++i) a += emb[i] * Wg1[i * Hh + j];
  tt[j] = reluf(a);
  __syncthreads();
  if (j < 12) {
    float o = bg2[j];
    for (int i = 0; i < Hh; ++i) o += tt[i] * Wg2[i * 12 + j];
    out[g * 12 + j] = o;
  }
}

extern "C" void kernel_launch(void* const* d_in, const int* in_sizes, int n_in,
                              void* d_out, int out_size, void* d_ws, size_t ws_size,
                              hipStream_t stream) {
  const int* x = (const int*)d_in[0];
  const int* eidx32 = (const int*)d_in[1];
  const int* eattr = (const int*)d_in[2];
  const float* atom_tab = (const float*)d_in[4];
  const float* bond_tab = (const float*)d_in[5];
  const float* W_m1 = (const float*)d_in[6];
  const float* b_m1 = (const float*)d_in[7];
  const float* W_m2 = (const float*)d_in[8];
  const float* b_m2 = (const float*)d_in[9];
  const float* W_me = (const float*)d_in[10];
  const float* b_me = (const float*)d_in[11];
  const float* b_mg = (const float*)d_in[13];
  const float* W_h1 = (const float*)d_in[14];
  const float* b_h1 = (const float*)d_in[15];
  const float* W_h2 = (const float*)d_in[16];
  const float* b_h2 = (const float*)d_in[17];
  const float* W_o1 = (const float*)d_in[18];
  const float* b_o1 = (const float*)d_in[19];
  const float* W_o2 = (const float*)d_in[20];
  const float* b_o2 = (const float*)d_in[21];
  const float* Wg1 = (const float*)d_in[22];
  const float* bg1 = (const float*)d_in[23];
  const float* Wg2 = (const float*)d_in[24];
  const float* bg2 = (const float*)d_in[25];
  float* out = (float*)d_out;

  char* ws = (char*)d_ws;
  float* nf = (float*)(ws);                                 // 2MB
  float* hidA = (float*)(ws + (2u << 20));                  // 2MB
  float* hidB = (float*)(ws + (4u << 20));                  // 2MB
  float* m1 = (float*)(ws + (6u << 20));                    // 2MB
  float* m2 = (float*)(ws + (8u << 20));                    // 2MB
  unsigned* aggk = (unsigned*)(ws + (10u << 20));           // 2MB
  int* win = (int*)(ws + (12u << 20));                      // 2MB (dead after k_collect)
  ushort_t* wt = (ushort_t*)(ws + (12u << 20));             // 256KB (reuses win region)
  float* bf = (float*)(ws + (14u << 20));                   // 256KB
  float* me = (float*)(ws + (14u << 20) + (256u << 10));    // 256KB
  unsigned* recs = (unsigned*)(ws + (14u << 20) + (512u << 10));  // 256KB
  int* cnt = (int*)(ws + (14u << 20) + (768u << 10));       // 4B
  int* eflag = cnt + 1;                                     // 4B

  hipMemsetAsync(win, 0xFF, GNN * sizeof(int), stream);
  hipMemsetAsync(cnt, 0, sizeof(int), stream);
  k_detect<<<1, 128, 0, stream>>>(eidx32, eflag);
  k_node_encode<<<2048, 256, 0, stream>>>(x, atom_tab, nf, hidA);
  k_bond_fts<<<256, 256, 0, stream>>>(bond_tab, bf);
  k_scatter_win<<<256, 256, 0, stream>>>(eidx32, eflag, win);
  k_collect<<<2048, 256, 0, stream>>>(win, eattr, recs, cnt);
  k_wprep<<<256, 256, 0, stream>>>(W_h1, W_h2, wt);   // after k_collect: win region dead

  float* hc = hidA;
  float* hn = hidB;
  for (int l = 0; l < 2; ++l) {
    const ushort_t* wt1h = wt + ((l * 2 + 0) * 2 + 0) * 16384;
    const ushort_t* wt1l = wt + ((l * 2 + 0) * 2 + 1) * 16384;
    const ushort_t* wt2h = wt + ((l * 2 + 1) * 2 + 0) * 16384;
    const ushort_t* wt2l = wt + ((l * 2 + 1) * 2 + 1) * 16384;
    k_me_init<<<256, 256, 0, stream>>>(bf, W_me + l * Hh * Hh, b_me + l * Hh,
                                       b_mg + l * Hh, me, aggk);
    k_m12<<<256, 256, 0, stream>>>(nf, hc, W_m1 + l * 2 * Hh * Hh, b_m1 + l * Hh,
                                   W_m2 + l * 2 * Hh * Hh, b_m2 + l * Hh, m1, m2);
    k_edge<<<1024, 256, 0, stream>>>(recs, cnt, m1, m2, me, wt1h, wt1l, wt2h, wt2l,
                                     b_h1 + l * Hh, b_h2 + l * Hh, aggk);
    k_out<<<256, 256, 0, stream>>>(nf, hc, aggk, W_o1 + l * 2 * Hh * Hh,
                                   b_o1 + l * Hh, W_o2 + l * Hh * Hh, b_o2 + l * Hh,
                                   hn);
    float* t = hc; hc = hn; hn = t;
  }
  k_head<<<32, 128, 0, stream>>>(hc, Wg1, bg1, Wg2, bg2, out);
}

// Round 4
// 391.904 us; speedup vs baseline: 1.5316x; 1.2687x over previous
//
#include <hip/hip_runtime.h>

#define Gg   32
#define Nn   128
#define Hh   128
#define Ee   65536
#define GN   4096      // Gg*Nn
#define GNN  524288    // Gg*Nn*Nn
#define SEG  1024      // win entries per compaction block
#define NSEG 512       // GNN / SEG

typedef unsigned short ushort_t;
typedef __attribute__((ext_vector_type(8))) __bf16 bf16x8;
typedef __attribute__((ext_vector_type(4))) float f32x4;

__device__ __forceinline__ float reluf(float x) { return x > 0.f ? x : 0.f; }

// monotone float <-> u32 key (for atomicMax on floats incl. negatives)
__device__ __forceinline__ unsigned fkey(float f) {
  unsigned u = __float_as_uint(f);
  return (u & 0x80000000u) ? ~u : (u | 0x80000000u);
}
__device__ __forceinline__ float funkey(unsigned k) {
  unsigned u = (k & 0x80000000u) ? (k ^ 0x80000000u) : ~k;
  return __uint_as_float(u);
}

// round-to-nearest-even f32 -> bf16 bits
__device__ __forceinline__ ushort_t bfh(float x) {
  unsigned u = __float_as_uint(x);
  return (ushort_t)((u + 0x7FFFu + ((u >> 16) & 1u)) >> 16);
}
__device__ __forceinline__ void split2(float x, ushort_t& h, ushort_t& l) {
  h = bfh(x);
  float hf = __uint_as_float(((unsigned)h) << 16);
  l = bfh(x - hf);
}

// ---------------- edge_index layout detection ----------------
__global__ __launch_bounds__(128) void k_detect(const int* __restrict__ e32,
                                                int* __restrict__ flag) {
  __shared__ int s;
  if (threadIdx.x == 0) s = 0;
  __syncthreads();
  if (e32[2 * threadIdx.x + 1] != 0) atomicOr(&s, 1);
  __syncthreads();
  if (threadIdx.x == 0) *flag = s;  // 1 => int32 layout, 0 => int64 layout
}

// ---------------- encoders ----------------
__global__ __launch_bounds__(256) void k_node_encode(const int* __restrict__ x,
                                                     const float* __restrict__ atom_tab,
                                                     float* __restrict__ nf,
                                                     float* __restrict__ hid) {
  int t = blockIdx.x * 256 + threadIdx.x;      // over GN*Hh
  int v = t >> 7, h = t & 127;
  float s = 0.f;
#pragma unroll
  for (int f = 0; f < 9; ++f) {
    int idx = x[v * 9 + f];
    s += atom_tab[(f * 119 + idx) * Hh + h];
  }
  nf[t] = s;
  hid[t] = 0.f;
}

__global__ __launch_bounds__(256) void k_bond_fts(const float* __restrict__ bond_tab,
                                                  float* __restrict__ bf) {
  int t = blockIdx.x * 256 + threadIdx.x;      // 512*128
  int c = t >> 7, h = t & 127;
  int a0 = c & 7, a1 = (c >> 3) & 7, a2 = (c >> 6) & 7;
  bf[t] = bond_tab[(0 * 8 + a0) * Hh + h] + bond_tab[(1 * 8 + a1) * Hh + h] +
          bond_tab[(2 * 8 + a2) * Hh + h];
}

// ---------------- edge winner: win indexed by (g, d, s); last edge wins ----------
__global__ __launch_bounds__(256) void k_scatter_win(const int* __restrict__ e32,
                                                     const int* __restrict__ flag,
                                                     int* __restrict__ win) {
  int e = blockIdx.x * 256 + threadIdx.x;
  int sg, dg;
  if (*flag) { sg = e32[e]; dg = e32[Ee + e]; }
  else       { sg = e32[2 * e]; dg = e32[2 * Ee + 2 * e]; }
  int g = sg / Nn;
  int s = sg % Nn;
  int d = dg % Nn;
  atomicMax(&win[(g * Nn + d) * Nn + s], e);   // destination-major
}

// ---------------- compaction: count / scan / fill (no contended atomics) --------
__global__ __launch_bounds__(256) void k_count(const int* __restrict__ win,
                                               int* __restrict__ blkcnt) {
  int tid = threadIdx.x;
  int4 v = *((const int4*)(win + blockIdx.x * SEG) + tid);
  int c = (v.x >= 0) + (v.y >= 0) + (v.z >= 0) + (v.w >= 0);
  __shared__ int sred[4];
#pragma unroll
  for (int off = 32; off; off >>= 1) c += __shfl_down(c, off, 64);
  if ((tid & 63) == 0) sred[tid >> 6] = c;
  __syncthreads();
  if (tid == 0) blkcnt[blockIdx.x] = sred[0] + sred[1] + sred[2] + sred[3];
}

__global__ __launch_bounds__(512) void k_scan(const int* __restrict__ blkcnt,
                                              int* __restrict__ blkoff,
                                              int* __restrict__ cnt) {
  int tid = threadIdx.x;            // 512 threads = 8 waves
  int v = blkcnt[tid];
  int x = v;
#pragma unroll
  for (int off = 1; off < 64; off <<= 1) {
    int y = __shfl_up(x, off, 64);
    if ((tid & 63) >= off) x += y;
  }
  __shared__ int wsum[8], woff[8];
  if ((tid & 63) == 63) wsum[tid >> 6] = x;
  __syncthreads();
  if (tid == 0) {
    int a = 0;
#pragma unroll
    for (int i = 0; i < 8; ++i) { woff[i] = a; a += wsum[i]; }
    *cnt = a;
  }
  __syncthreads();
  blkoff[tid] = x - v + woff[tid >> 6];   // exclusive prefix
}

__global__ __launch_bounds__(256) void k_fill(const int* __restrict__ win,
                                              const int* __restrict__ eattr,
                                              const int* __restrict__ blkoff,
                                              unsigned* __restrict__ recs) {
  int tid = threadIdx.x;
  int base_idx = blockIdx.x * SEG + tid * 4;
  int4 v = *((const int4*)(win + blockIdx.x * SEG) + tid);
  int e[4] = {v.x, v.y, v.z, v.w};
  int c = (v.x >= 0) + (v.y >= 0) + (v.z >= 0) + (v.w >= 0);
  int x = c;
#pragma unroll
  for (int off = 1; off < 64; off <<= 1) {
    int y = __shfl_up(x, off, 64);
    if ((tid & 63) >= off) x += y;
  }
  __shared__ int wsum[4], woff[4];
  if ((tid & 63) == 63) wsum[tid >> 6] = x;
  __syncthreads();
  if (tid == 0) {
    int a = 0;
#pragma unroll
    for (int i = 0; i < 4; ++i) { woff[i] = a; a += wsum[i]; }
  }
  __syncthreads();
  int pos = blkoff[blockIdx.x] + woff[tid >> 6] + x - c;
#pragma unroll
  for (int i = 0; i < 4; ++i) {
    if (e[i] >= 0) {
      int a0 = eattr[e[i] * 3 + 0], a1 = eattr[e[i] * 3 + 1], a2 = eattr[e[i] * 3 + 2];
      unsigned code = (unsigned)(a0 + (a1 << 3) + (a2 << 6));
      recs[pos++] = ((unsigned)(base_idx + i) << 9) | code;
    }
  }
}

// ---------------- weight prep: W_h1/W_h2 -> transposed hi/lo bf16 ----------------
__global__ __launch_bounds__(256) void k_wprep(const float* __restrict__ W_h1,
                                               const float* __restrict__ W_h2,
                                               ushort_t* __restrict__ wt) {
  int t = blockIdx.x * 256 + threadIdx.x;      // 2*2*16384
  int l = t >> 15;
  int m = (t >> 14) & 1;
  int e = t & 16383;
  int n = e & 127, k = e >> 7;
  const float* W = (m == 0 ? W_h1 : W_h2) + l * 16384;
  float v = W[k * 128 + n];
  ushort_t h, lo;
  split2(v, h, lo);
  int base = ((l * 2 + m) * 2) * 16384;
  wt[base + n * 128 + k] = h;
  wt[base + 16384 + n * 128 + k] = lo;
}

// ---------------- me table + agg init (fused) ----------------
__global__ __launch_bounds__(256) void k_me_init(const float* __restrict__ bf,
                                                 const float* __restrict__ W_me,
                                                 const float* __restrict__ b_me,
                                                 const float* __restrict__ b_mg,
                                                 float* __restrict__ me,
                                                 unsigned* __restrict__ aggk) {
  __shared__ float v[2][128];
  int tid = threadIdx.x;
  int half = tid >> 7, j = tid & 127;
  int c = blockIdx.x * 2 + half;
  v[half][j] = bf[c * 128 + j];
  __syncthreads();
  float acc = b_me[j] + b_mg[j];
  for (int i = 0; i < 128; ++i) acc += v[half][i] * W_me[i * 128 + j];
  me[c * 128 + j] = acc;
  unsigned key = fkey(-1.0e9f);
#pragma unroll
  for (int i = 0; i < 8; ++i) aggk[blockIdx.x * 2048 + i * 256 + tid] = key;
}

// ---------------- m1,m2 = [nf|hid] @ W_m1 / W_m2 ----------------
__global__ __launch_bounds__(256) void k_m12(const float* __restrict__ nf,
                                             const float* __restrict__ hid,
                                             const float* __restrict__ W1,
                                             const float* __restrict__ bi1,
                                             const float* __restrict__ W2,
                                             const float* __restrict__ bi2,
                                             float* __restrict__ m1,
                                             float* __restrict__ m2) {
  __shared__ float As[16][256];
  __shared__ float Wt1[16][128];
  __shared__ float Wt2[16][128];
  int tid = threadIdx.x;
  int v0 = blockIdx.x * 16;
#pragma unroll
  for (int i = 0; i < 16; ++i) {
    int e = tid + i * 256;
    int row = e >> 8, col = e & 255;
    As[row][col] = (col < 128) ? nf[(v0 + row) * Hh + col]
                               : hid[(v0 + row) * Hh + (col - 128)];
  }
  float a1[2][4], a2[2][4];
#pragma unroll
  for (int i = 0; i < 2; ++i)
#pragma unroll
    for (int j = 0; j < 4; ++j) { a1[i][j] = 0.f; a2[i][j] = 0.f; }
  int c0 = tid & 31, r0 = tid >> 5;
  for (int k0 = 0; k0 < 256; k0 += 16) {
    __syncthreads();
#pragma unroll
    for (int i = 0; i < 8; ++i) {
      int e = tid + i * 256;
      int rr = e >> 7, cc = e & 127;
      Wt1[rr][cc] = W1[(k0 + rr) * Hh + cc];
      Wt2[rr][cc] = W2[(k0 + rr) * Hh + cc];
    }
    __syncthreads();
#pragma unroll
    for (int kk = 0; kk < 16; ++kk) {
      float a[2] = {As[r0][k0 + kk], As[r0 + 8][k0 + kk]};
      float w1[4], w2[4];
#pragma unroll
      for (int j = 0; j < 4; ++j) { w1[j] = Wt1[kk][c0 + 32 * j]; w2[j] = Wt2[kk][c0 + 32 * j]; }
#pragma unroll
      for (int i = 0; i < 2; ++i)
#pragma unroll
        for (int j = 0; j < 4; ++j) { a1[i][j] += a[i] * w1[j]; a2[i][j] += a[i] * w2[j]; }
    }
  }
#pragma unroll
  for (int i = 0; i < 2; ++i)
#pragma unroll
    for (int j = 0; j < 4; ++j) {
      int r = v0 + r0 + 8 * i, c = c0 + 32 * j;
      m1[r * Hh + c] = a1[i][j] + bi1[c];
      m2[r * Hh + c] = a2[i][j] + bi2[c];
    }
}

// ---------------- MFMA helpers ----------------
__device__ __forceinline__ void load_afrag(const ushort_t (*MH)[136],
                                           const ushort_t (*ML)[136],
                                           int row, int lg,
                                           bf16x8 ah[4], bf16x8 al[4]) {
#pragma unroll
  for (int kf = 0; kf < 4; ++kf) {
    ah[kf] = *(const bf16x8*)&MH[row][lg * 8 + 32 * kf];
    al[kf] = *(const bf16x8*)&ML[row][lg * 8 + 32 * kf];
  }
}

__device__ __forceinline__ void wave_gemm(const ushort_t* __restrict__ wth,
                                          const ushort_t* __restrict__ wtl,
                                          const bf16x8 ah[4], const bf16x8 al[4],
                                          int lr, int lg, f32x4 acc[8]) {
#pragma unroll
  for (int nf = 0; nf < 8; ++nf) {
    acc[nf] = (f32x4){0.f, 0.f, 0.f, 0.f};
    const ushort_t* bh_base = wth + (16 * nf + lr) * 128 + lg * 8;
    const ushort_t* bl_base = wtl + (16 * nf + lr) * 128 + lg * 8;
#pragma unroll
    for (int kf = 0; kf < 4; ++kf) {
      bf16x8 bh = *(const bf16x8*)(bh_base + 32 * kf);
      bf16x8 bl = *(const bf16x8*)(bl_base + 32 * kf);
      acc[nf] = __builtin_amdgcn_mfma_f32_16x16x32_bf16(ah[kf], bh, acc[nf], 0, 0, 0);
      acc[nf] = __builtin_amdgcn_mfma_f32_16x16x32_bf16(ah[kf], bl, acc[nf], 0, 0, 0);
      acc[nf] = __builtin_amdgcn_mfma_f32_16x16x32_bf16(al[kf], bh, acc[nf], 0, 0, 0);
    }
  }
}

// ---------------- edge phase (MFMA bf16x3 + run-dedup scatter) ----------------
__global__ __launch_bounds__(256) void k_edge(const unsigned* __restrict__ recs,
                                              const int* __restrict__ cnt,
                                              const float* __restrict__ m1,
                                              const float* __restrict__ m2,
                                              const float* __restrict__ me,
                                              const ushort_t* __restrict__ wt1h,
                                              const ushort_t* __restrict__ wt1l,
                                              const ushort_t* __restrict__ wt2h,
                                              const ushort_t* __restrict__ wt2l,
                                              const float* __restrict__ b_h1,
                                              const float* __restrict__ b_h2,
                                              unsigned* __restrict__ aggk) {
  __shared__ ushort_t MH[64][136];
  __shared__ ushort_t ML[64][136];
  __shared__ unsigned srec[64];
  int tid = threadIdx.x;
  int n = *cnt;
  if (tid < 64) {
    int r = blockIdx.x * 64 + tid;
    srec[tid] = (r < n) ? recs[r] : 0xFFFFFFFFu;
  }
  __syncthreads();
  // build M tile (hi/lo bf16); rec idx = (g*128 + d)*128 + s
  {
    int c = tid & 127, rr = tid >> 7;
#pragma unroll
    for (int i = 0; i < 32; ++i) {
      int r = rr + i * 2;
      unsigned rec = srec[r];
      float v = 0.f;
      if (rec != 0xFFFFFFFFu) {
        int code = rec & 511;
        unsigned idx = rec >> 9;
        int s = idx & 127, d = (idx >> 7) & 127, g = idx >> 14;
        v = reluf(m1[((g << 7) + d) * Hh + c] + m2[((g << 7) + s) * Hh + c] +
                  me[code * Hh + c]);
      }
      ushort_t h, l;
      split2(v, h, l);
      MH[r][c] = h;
      ML[r][c] = l;
    }
  }
  __syncthreads();

  int lane = tid & 63, wid = tid >> 6;
  int lr = lane & 15, lg = lane >> 4;
  float b1v[8], b2v[8];
#pragma unroll
  for (int nf = 0; nf < 8; ++nf) {
    b1v[nf] = b_h1[16 * nf + lr];
    b2v[nf] = b_h2[16 * nf + lr];
  }
  int arow = 16 * wid + lr;
  bf16x8 ah[4], al[4];
  load_afrag(MH, ML, arow, lg, ah, al);
  f32x4 acc[8];
  wave_gemm(wt1h, wt1l, ah, al, lr, lg, acc);
  // T = relu(acc + b1) -> back into MH/ML (wave-private rows)
#pragma unroll
  for (int nf = 0; nf < 8; ++nf)
#pragma unroll
    for (int reg = 0; reg < 4; ++reg) {
      float t = reluf(acc[nf][reg] + b1v[nf]);
      int row = 16 * wid + lg * 4 + reg;
      int col = 16 * nf + lr;
      ushort_t h, l;
      split2(t, h, l);
      MH[row][col] = h;
      ML[row][col] = l;
    }
  __syncthreads();
  load_afrag(MH, ML, arow, lg, ah, al);
  wave_gemm(wt2h, wt2l, ah, al, lr, lg, acc);
  // park f32 result bits in MH/ML (wave-private rows)
#pragma unroll
  for (int nf = 0; nf < 8; ++nf)
#pragma unroll
    for (int reg = 0; reg < 4; ++reg) {
      int row = 16 * wid + lg * 4 + reg;
      int col = 16 * nf + lr;
      unsigned b = __float_as_uint(acc[nf][reg] + b2v[nf]);
      MH[row][col] = (ushort_t)(b >> 16);
      ML[row][col] = (ushort_t)(b & 0xFFFFu);
    }
  __syncthreads();
  // run-dedup scatter: rows sorted by (g,d) = rec>>16; one atomic per run per col
  {
    int c = tid & 127, half = tid >> 7;
    int rbeg = half * 32, rend = rbeg + 32;
    unsigned curkey = 0xFFFFu;
    float best = -3.0e38f;
    for (int r = rbeg; r < rend; ++r) {
      unsigned rec = srec[r];
      unsigned key = rec >> 16;   // g*128+d (<=0xFFF) or 0xFFFF if invalid
      if (key != curkey) {
        if (curkey != 0xFFFFu)
          atomicMax(aggk + (curkey << 7) + c, fkey(best));
        curkey = key;
        best = -3.0e38f;
      }
      if (key != 0xFFFFu) {
        unsigned b = ((unsigned)MH[r][c] << 16) | (unsigned)ML[r][c];
        best = fmaxf(best, __uint_as_float(b));
      }
    }
    if (curkey != 0xFFFFu)
      atomicMax(aggk + (curkey << 7) + c, fkey(best));
  }
}

// ---------------- hid update ----------------
__global__ __launch_bounds__(256) void k_out(const float* __restrict__ nf,
                                             const float* __restrict__ hid,
                                             const unsigned* __restrict__ aggk,
                                             const float* __restrict__ Wo1,
                                             const float* __restrict__ bo1,
                                             const float* __restrict__ Wo2,
                                             const float* __restrict__ bo2,
                                             float* __restrict__ hidn) {
  __shared__ float As[16][384];
  __shared__ float Wt[16][128];
  int tid = threadIdx.x;
  int v0 = blockIdx.x * 16;
#pragma unroll
  for (int seg = 0; seg < 3; ++seg) {
#pragma unroll
    for (int i = 0; i < 8; ++i) {
      int e = tid + i * 256;
      int row = e >> 7, col = e & 127;
      float val;
      if (seg == 0) val = nf[(v0 + row) * Hh + col];
      else if (seg == 1) val = hid[(v0 + row) * Hh + col];
      else val = funkey(aggk[(v0 + row) * Hh + col]);
      As[row][seg * 128 + col] = val;
    }
  }
  float acc[2][4];
#pragma unroll
  for (int i = 0; i < 2; ++i)
#pragma unroll
    for (int j = 0; j < 4; ++j) acc[i][j] = 0.f;
  int c0 = tid & 31, r0 = tid >> 5;
  for (int k0 = 0; k0 < 384; k0 += 16) {
    __syncthreads();
#pragma unroll
    for (int i = 0; i < 8; ++i) {
      int e = tid + i * 256;
      int rr = e >> 7, cc = e & 127;
      int k = k0 + rr;
      Wt[rr][cc] = (k < 256) ? Wo1[k * Hh + cc] : Wo2[(k - 256) * Hh + cc];
    }
    __syncthreads();
#pragma unroll
    for (int kk = 0; kk < 16; ++kk) {
      float a[2] = {As[r0][k0 + kk], As[r0 + 8][k0 + kk]};
      float w[4];
#pragma unroll
      for (int j = 0; j < 4; ++j) w[j] = Wt[kk][c0 + 32 * j];
#pragma unroll
      for (int i = 0; i < 2; ++i)
#pragma unroll
        for (int j = 0; j < 4; ++j) acc[i][j] += a[i] * w[j];
    }
  }
#pragma unroll
  for (int i = 0; i < 2; ++i)
#pragma unroll
    for (int j = 0; j < 4; ++j) {
      int r = v0 + r0 + 8 * i, c = c0 + 32 * j;
      hidn[r * Hh + c] = reluf(acc[i][j] + bo1[c] + bo2[c]);
    }
}

// ---------------- readout head ----------------
__global__ __launch_bounds__(128) void k_head(const float* __restrict__ hid,
                                              const float* __restrict__ Wg1,
                                              const float* __restrict__ bg1,
                                              const float* __restrict__ Wg2,
                                              const float* __restrict__ bg2,
                                              float* __restrict__ out) {
  __shared__ float emb[Hh];
  __shared__ float tt[Hh];
  int g = blockIdx.x, j = threadIdx.x;
  float s = 0.f;
  for (int n = 0; n < Nn; ++n) s += hid[(g * Nn + n) * Hh + j];
  emb[j] = s * (1.f / Nn);
  __syncthreads();
  float a = bg1[j];
  for (int i = 0; i < Hh; ++i) a += emb[i] * Wg1[i * Hh + j];
  tt[j] = reluf(a);
  __syncthreads();
  if (j < 12) {
    float o = bg2[j];
    for (int i = 0; i < Hh; ++i) o += tt[i] * Wg2[i * 12 + j];
    out[g * 12 + j] = o;
  }
}

extern "C" void kernel_launch(void* const* d_in, const int* in_sizes, int n_in,
                              void* d_out, int out_size, void* d_ws, size_t ws_size,
                              hipStream_t stream) {
  const int* x = (const int*)d_in[0];
  const int* eidx32 = (const int*)d_in[1];
  const int* eattr = (const int*)d_in[2];
  const float* atom_tab = (const float*)d_in[4];
  const float* bond_tab = (const float*)d_in[5];
  const float* W_m1 = (const float*)d_in[6];
  const float* b_m1 = (const float*)d_in[7];
  const float* W_m2 = (const float*)d_in[8];
  const float* b_m2 = (const float*)d_in[9];
  const float* W_me = (const float*)d_in[10];
  const float* b_me = (const float*)d_in[11];
  const float* b_mg = (const float*)d_in[13];
  const float* W_h1 = (const float*)d_in[14];
  const float* b_h1 = (const float*)d_in[15];
  const float* W_h2 = (const float*)d_in[16];
  const float* b_h2 = (const float*)d_in[17];
  const float* W_o1 = (const float*)d_in[18];
  const float* b_o1 = (const float*)d_in[19];
  const float* W_o2 = (const float*)d_in[20];
  const float* b_o2 = (const float*)d_in[21];
  const float* Wg1 = (const float*)d_in[22];
  const float* bg1 = (const float*)d_in[23];
  const float* Wg2 = (const float*)d_in[24];
  const float* bg2 = (const float*)d_in[25];
  float* out = (float*)d_out;

  char* ws = (char*)d_ws;
  float* nf = (float*)(ws);                                 // 2MB
  float* hidA = (float*)(ws + (2u << 20));                  // 2MB
  float* hidB = (float*)(ws + (4u << 20));                  // 2MB
  float* m1 = (float*)(ws + (6u << 20));                    // 2MB
  float* m2 = (float*)(ws + (8u << 20));                    // 2MB
  unsigned* aggk = (unsigned*)(ws + (10u << 20));           // 2MB
  int* win = (int*)(ws + (12u << 20));                      // 2MB (dead after k_fill)
  ushort_t* wt = (ushort_t*)(ws + (14u << 20));             // 256KB
  float* bf = (float*)(ws + (14u << 20) + (256u << 10));    // 256KB
  float* me = (float*)(ws + (14u << 20) + (512u << 10));    // 256KB
  unsigned* recs = (unsigned*)(ws + (14u << 20) + (768u << 10));  // 256KB
  int* blkcnt = (int*)(ws + (15u << 20));                   // 2KB
  int* blkoff = blkcnt + NSEG;                              // 2KB
  int* cnt = blkoff + NSEG;                                 // 4B
  int* eflag = cnt + 1;                                     // 4B

  hipMemsetAsync(win, 0xFF, GNN * sizeof(int), stream);
  k_detect<<<1, 128, 0, stream>>>(eidx32, eflag);
  k_node_encode<<<2048, 256, 0, stream>>>(x, atom_tab, nf, hidA);
  k_bond_fts<<<256, 256, 0, stream>>>(bond_tab, bf);
  k_scatter_win<<<256, 256, 0, stream>>>(eidx32, eflag, win);
  k_count<<<NSEG, 256, 0, stream>>>(win, blkcnt);
  k_scan<<<1, 512, 0, stream>>>(blkcnt, blkoff, cnt);
  k_fill<<<NSEG, 256, 0, stream>>>(win, eattr, blkoff, recs);
  k_wprep<<<256, 256, 0, stream>>>(W_h1, W_h2, wt);

  float* hc = hidA;
  float* hn = hidB;
  for (int l = 0; l < 2; ++l) {
    const ushort_t* wt1h = wt + ((l * 2 + 0) * 2 + 0) * 16384;
    const ushort_t* wt1l = wt + ((l * 2 + 0) * 2 + 1) * 16384;
    const ushort_t* wt2h = wt + ((l * 2 + 1) * 2 + 0) * 16384;
    const ushort_t* wt2l = wt + ((l * 2 + 1) * 2 + 1) * 16384;
    k_me_init<<<256, 256, 0, stream>>>(bf, W_me + l * Hh * Hh, b_me + l * Hh,
                                       b_mg + l * Hh, me, aggk);
    k_m12<<<256, 256, 0, stream>>>(nf, hc, W_m1 + l * 2 * Hh * Hh, b_m1 + l * Hh,
                                   W_m2 + l * 2 * Hh * Hh, b_m2 + l * Hh, m1, m2);
    k_edge<<<1024, 256, 0, stream>>>(recs, cnt, m1, m2, me, wt1h, wt1l, wt2h, wt2l,
                                     b_h1 + l * Hh, b_h2 + l * Hh, aggk);
    k_out<<<256, 256, 0, stream>>>(nf, hc, aggk, W_o1 + l * 2 * Hh * Hh,
                                   b_o1 + l * Hh, W_o2 + l * Hh * Hh, b_o2 + l * Hh,
                                   hn);
    float* t = hc; hc = hn; hn = t;
  }
  k_head<<<32, 128, 0, stream>>>(hc, Wg1, bg1, Wg2, bg2, out);
}

// Round 6
// 311.191 us; speedup vs baseline: 1.9289x; 1.2594x over previous
//
#include <hip/hip_runtime.h>

#define Gg   32
#define Nn   128
#define Hh   128
#define Ee   65536
#define GN   4096      // Gg*Nn
#define GNN  524288    // Gg*Nn*Nn
#define SEG  1024      // win entries per compaction block
#define NSEG 512       // GNN / SEG

typedef unsigned short ushort_t;
typedef __attribute__((ext_vector_type(8))) __bf16 bf16x8;
typedef __attribute__((ext_vector_type(4))) float f32x4;
struct us4 { ushort_t a, b, c, d; };

__device__ __forceinline__ float reluf(float x) { return x > 0.f ? x : 0.f; }

// monotone float <-> u32 key (for atomicMax on floats incl. negatives)
__device__ __forceinline__ unsigned fkey(float f) {
  unsigned u = __float_as_uint(f);
  return (u & 0x80000000u) ? ~u : (u | 0x80000000u);
}
__device__ __forceinline__ float funkey(unsigned k) {
  unsigned u = (k & 0x80000000u) ? (k ^ 0x80000000u) : ~k;
  return __uint_as_float(u);
}

// round-to-nearest-even f32 -> bf16 bits
__device__ __forceinline__ ushort_t bfh(float x) {
  unsigned u = __float_as_uint(x);
  return (ushort_t)((u + 0x7FFFu + ((u >> 16) & 1u)) >> 16);
}
__device__ __forceinline__ void split2(float x, ushort_t& h, ushort_t& l) {
  h = bfh(x);
  float hf = __uint_as_float(((unsigned)h) << 16);
  l = bfh(x - hf);
}

// ---------------- edge_index layout detection ----------------
__global__ __launch_bounds__(128) void k_detect(const int* __restrict__ e32,
                                                int* __restrict__ flag) {
  __shared__ int s;
  if (threadIdx.x == 0) s = 0;
  __syncthreads();
  if (e32[2 * threadIdx.x + 1] != 0) atomicOr(&s, 1);
  __syncthreads();
  if (threadIdx.x == 0) *flag = s;  // 1 => int32 layout, 0 => int64 layout
}

// ---------------- encoders ----------------
__global__ __launch_bounds__(256) void k_node_encode(const int* __restrict__ x,
                                                     const float* __restrict__ atom_tab,
                                                     float* __restrict__ nf,
                                                     float* __restrict__ hid) {
  int t = blockIdx.x * 256 + threadIdx.x;      // over GN*Hh
  int v = t >> 7, h = t & 127;
  float s = 0.f;
#pragma unroll
  for (int f = 0; f < 9; ++f) {
    int idx = x[v * 9 + f];
    s += atom_tab[(f * 119 + idx) * Hh + h];
  }
  nf[t] = s;
  hid[t] = 0.f;
}

__global__ __launch_bounds__(256) void k_bond_fts(const float* __restrict__ bond_tab,
                                                  float* __restrict__ bf) {
  int t = blockIdx.x * 256 + threadIdx.x;      // 512*128
  int c = t >> 7, h = t & 127;
  int a0 = c & 7, a1 = (c >> 3) & 7, a2 = (c >> 6) & 7;
  bf[t] = bond_tab[(0 * 8 + a0) * Hh + h] + bond_tab[(1 * 8 + a1) * Hh + h] +
          bond_tab[(2 * 8 + a2) * Hh + h];
}

// ---------------- edge winner: win indexed by (g, d, s); last edge wins ----------
__global__ __launch_bounds__(256) void k_scatter_win(const int* __restrict__ e32,
                                                     const int* __restrict__ flag,
                                                     int* __restrict__ win) {
  int e = blockIdx.x * 256 + threadIdx.x;
  int sg, dg;
  if (*flag) { sg = e32[e]; dg = e32[Ee + e]; }
  else       { sg = e32[2 * e]; dg = e32[2 * Ee + 2 * e]; }
  int g = sg / Nn;
  int s = sg % Nn;
  int d = dg % Nn;
  atomicMax(&win[(g * Nn + d) * Nn + s], e);   // destination-major
}

// ---------------- compaction: count / scan / fill (no contended atomics) --------
__global__ __launch_bounds__(256) void k_count(const int* __restrict__ win,
                                               int* __restrict__ blkcnt) {
  int tid = threadIdx.x;
  int4 v = *((const int4*)(win + blockIdx.x * SEG) + tid);
  int c = (v.x >= 0) + (v.y >= 0) + (v.z >= 0) + (v.w >= 0);
  __shared__ int sred[4];
#pragma unroll
  for (int off = 32; off; off >>= 1) c += __shfl_down(c, off, 64);
  if ((tid & 63) == 0) sred[tid >> 6] = c;
  __syncthreads();
  if (tid == 0) blkcnt[blockIdx.x] = sred[0] + sred[1] + sred[2] + sred[3];
}

__global__ __launch_bounds__(512) void k_scan(const int* __restrict__ blkcnt,
                                              int* __restrict__ blkoff,
                                              int* __restrict__ cnt) {
  int tid = threadIdx.x;            // 512 threads = 8 waves
  int v = blkcnt[tid];
  int x = v;
#pragma unroll
  for (int off = 1; off < 64; off <<= 1) {
    int y = __shfl_up(x, off, 64);
    if ((tid & 63) >= off) x += y;
  }
  __shared__ int wsum[8], woff[8];
  if ((tid & 63) == 63) wsum[tid >> 6] = x;
  __syncthreads();
  if (tid == 0) {
    int a = 0;
#pragma unroll
    for (int i = 0; i < 8; ++i) { woff[i] = a; a += wsum[i]; }
    *cnt = a;
  }
  __syncthreads();
  blkoff[tid] = x - v + woff[tid >> 6];   // exclusive prefix
}

__global__ __launch_bounds__(256) void k_fill(const int* __restrict__ win,
                                              const int* __restrict__ eattr,
                                              const int* __restrict__ blkoff,
                                              unsigned* __restrict__ recs) {
  int tid = threadIdx.x;
  int base_idx = blockIdx.x * SEG + tid * 4;
  int4 v = *((const int4*)(win + blockIdx.x * SEG) + tid);
  int e[4] = {v.x, v.y, v.z, v.w};
  int c = (v.x >= 0) + (v.y >= 0) + (v.z >= 0) + (v.w >= 0);
  int x = c;
#pragma unroll
  for (int off = 1; off < 64; off <<= 1) {
    int y = __shfl_up(x, off, 64);
    if ((tid & 63) >= off) x += y;
  }
  __shared__ int wsum[4], woff[4];
  if ((tid & 63) == 63) wsum[tid >> 6] = x;
  __syncthreads();
  if (tid == 0) {
    int a = 0;
#pragma unroll
    for (int i = 0; i < 4; ++i) { woff[i] = a; a += wsum[i]; }
  }
  __syncthreads();
  int pos = blkoff[blockIdx.x] + woff[tid >> 6] + x - c;
#pragma unroll
  for (int i = 0; i < 4; ++i) {
    if (e[i] >= 0) {
      int a0 = eattr[e[i] * 3 + 0], a1 = eattr[e[i] * 3 + 1], a2 = eattr[e[i] * 3 + 2];
      unsigned code = (unsigned)(a0 + (a1 << 3) + (a2 << 6));
      recs[pos++] = ((unsigned)(base_idx + i) << 9) | code;
    }
  }
}

// ---------------- weight prep: W_h1/W_h2 -> transposed hi/lo bf16 ----------------
// wt layout: [layer(2)][mat(2)][part(2)][n(128)][k(128)] ushort
__global__ __launch_bounds__(256) void k_wprep(const float* __restrict__ W_h1,
                                               const float* __restrict__ W_h2,
                                               ushort_t* __restrict__ wt) {
  int t = blockIdx.x * 256 + threadIdx.x;      // 2*2*16384
  int l = t >> 15;
  int m = (t >> 14) & 1;
  int e = t & 16383;
  int n = e & 127, k = e >> 7;
  const float* W = (m == 0 ? W_h1 : W_h2) + l * 16384;
  float v = W[k * 128 + n];
  ushort_t h, lo;
  split2(v, h, lo);
  int base = ((l * 2 + m) * 2) * 16384;
  wt[base + n * 128 + k] = h;
  wt[base + 16384 + n * 128 + k] = lo;
}

// ---------------- weight prep: [Wo1;Wo2] -> transposed hi/lo bf16 ----------------
// wo layout: [layer(2)][part(2)][n(128)][k(384)] ushort; grid (192, 2)
__global__ __launch_bounds__(256) void k_wprep_o(const float* __restrict__ W_o1,
                                                 const float* __restrict__ W_o2,
                                                 ushort_t* __restrict__ wo) {
  int e = blockIdx.x * 256 + threadIdx.x;      // 0 .. 49151  (= n*384 + k)
  int l = blockIdx.y;
  int n = e / 384, k = e - n * 384;
  float v = (k < 256) ? W_o1[(l * 256 + k) * 128 + n]
                      : W_o2[(l * 128 + (k - 256)) * 128 + n];
  ushort_t h, lo;
  split2(v, h, lo);
  wo[((l * 2 + 0) * 128 + n) * 384 + k] = h;
  wo[((l * 2 + 1) * 128 + n) * 384 + k] = lo;
}

// ---------------- me table + agg init (fused) ----------------
__global__ __launch_bounds__(256) void k_me_init(const float* __restrict__ bf,
                                                 const float* __restrict__ W_me,
                                                 const float* __restrict__ b_me,
                                                 const float* __restrict__ b_mg,
                                                 float* __restrict__ me,
                                                 unsigned* __restrict__ aggk) {
  __shared__ float v[2][128];
  int tid = threadIdx.x;
  int half = tid >> 7, j = tid & 127;
  int c = blockIdx.x * 2 + half;
  v[half][j] = bf[c * 128 + j];
  __syncthreads();
  float acc = b_me[j] + b_mg[j];
  for (int i = 0; i < 128; ++i) acc += v[half][i] * W_me[i * 128 + j];
  me[c * 128 + j] = acc;
  unsigned key = fkey(-1.0e9f);
#pragma unroll
  for (int i = 0; i < 8; ++i) aggk[blockIdx.x * 2048 + i * 256 + tid] = key;
}

// ---------------- m1,m2 = [nf|hid] @ W_m1 / W_m2 ----------------
__global__ __launch_bounds__(256) void k_m12(const float* __restrict__ nf,
                                             const float* __restrict__ hid,
                                             const float* __restrict__ W1,
                                             const float* __restrict__ bi1,
                                             const float* __restrict__ W2,
                                             const float* __restrict__ bi2,
                                             float* __restrict__ m1,
                                             float* __restrict__ m2) {
  __shared__ float As[16][256];
  __shared__ float Wt1[16][128];
  __shared__ float Wt2[16][128];
  int tid = threadIdx.x;
  int v0 = blockIdx.x * 16;
#pragma unroll
  for (int i = 0; i < 16; ++i) {
    int e = tid + i * 256;
    int row = e >> 8, col = e & 255;
    As[row][col] = (col < 128) ? nf[(v0 + row) * Hh + col]
                               : hid[(v0 + row) * Hh + (col - 128)];
  }
  float a1[2][4], a2[2][4];
#pragma unroll
  for (int i = 0; i < 2; ++i)
#pragma unroll
    for (int j = 0; j < 4; ++j) { a1[i][j] = 0.f; a2[i][j] = 0.f; }
  int c0 = tid & 31, r0 = tid >> 5;
  for (int k0 = 0; k0 < 256; k0 += 16) {
    __syncthreads();
#pragma unroll
    for (int i = 0; i < 8; ++i) {
      int e = tid + i * 256;
      int rr = e >> 7, cc = e & 127;
      Wt1[rr][cc] = W1[(k0 + rr) * Hh + cc];
      Wt2[rr][cc] = W2[(k0 + rr) * Hh + cc];
    }
    __syncthreads();
#pragma unroll
    for (int kk = 0; kk < 16; ++kk) {
      float a[2] = {As[r0][k0 + kk], As[r0 + 8][k0 + kk]};
      float w1[4], w2[4];
#pragma unroll
      for (int j = 0; j < 4; ++j) { w1[j] = Wt1[kk][c0 + 32 * j]; w2[j] = Wt2[kk][c0 + 32 * j]; }
#pragma unroll
      for (int i = 0; i < 2; ++i)
#pragma unroll
        for (int j = 0; j < 4; ++j) { a1[i][j] += a[i] * w1[j]; a2[i][j] += a[i] * w2[j]; }
    }
  }
#pragma unroll
  for (int i = 0; i < 2; ++i)
#pragma unroll
    for (int j = 0; j < 4; ++j) {
      int r = v0 + r0 + 8 * i, c = c0 + 32 * j;
      m1[r * Hh + c] = a1[i][j] + bi1[c];
      m2[r * Hh + c] = a2[i][j] + bi2[c];
    }
}

// ---------------- MFMA helpers ----------------
__device__ __forceinline__ void load_afrag(const ushort_t (*MH)[136],
                                           const ushort_t (*ML)[136],
                                           int row, int lg,
                                           bf16x8 ah[4], bf16x8 al[4]) {
#pragma unroll
  for (int kf = 0; kf < 4; ++kf) {
    ah[kf] = *(const bf16x8*)&MH[row][lg * 8 + 32 * kf];
    al[kf] = *(const bf16x8*)&ML[row][lg * 8 + 32 * kf];
  }
}

__device__ __forceinline__ void wave_gemm(const ushort_t* __restrict__ wth,
                                          const ushort_t* __restrict__ wtl,
                                          const bf16x8 ah[4], const bf16x8 al[4],
                                          int lr, int lg, f32x4 acc[8]) {
#pragma unroll
  for (int nf = 0; nf < 8; ++nf) {
    acc[nf] = (f32x4){0.f, 0.f, 0.f, 0.f};
    const ushort_t* bh_base = wth + (16 * nf + lr) * 128 + lg * 8;
    const ushort_t* bl_base = wtl + (16 * nf + lr) * 128 + lg * 8;
#pragma unroll
    for (int kf = 0; kf < 4; ++kf) {
      bf16x8 bh = *(const bf16x8*)(bh_base + 32 * kf);
      bf16x8 bl = *(const bf16x8*)(bl_base + 32 * kf);
      acc[nf] = __builtin_amdgcn_mfma_f32_16x16x32_bf16(ah[kf], bh, acc[nf], 0, 0, 0);
      acc[nf] = __builtin_amdgcn_mfma_f32_16x16x32_bf16(ah[kf], bl, acc[nf], 0, 0, 0);
      acc[nf] = __builtin_amdgcn_mfma_f32_16x16x32_bf16(al[kf], bh, acc[nf], 0, 0, 0);
    }
  }
}

// ---------------- edge phase (MFMA bf16x3 + run-dedup scatter) ----------------
__global__ __launch_bounds__(256) void k_edge(const unsigned* __restrict__ recs,
                                              const int* __restrict__ cnt,
                                              const float* __restrict__ m1,
                                              const float* __restrict__ m2,
                                              const float* __restrict__ me,
                                              const ushort_t* __restrict__ wt1h,
                                              const ushort_t* __restrict__ wt1l,
                                              const ushort_t* __restrict__ wt2h,
                                              const ushort_t* __restrict__ wt2l,
                                              const float* __restrict__ b_h1,
                                              const float* __restrict__ b_h2,
                                              unsigned* __restrict__ aggk) {
  __shared__ ushort_t MH[64][136];
  __shared__ ushort_t ML[64][136];
  __shared__ unsigned srec[64];
  int tid = threadIdx.x;
  int n = *cnt;
  if (tid < 64) {
    int r = blockIdx.x * 64 + tid;
    srec[tid] = (r < n) ? recs[r] : 0xFFFFFFFFu;
  }
  __syncthreads();
  // build M tile (hi/lo bf16); rec idx = (g*128 + d)*128 + s
  {
    int c = tid & 127, rr = tid >> 7;
#pragma unroll
    for (int i = 0; i < 32; ++i) {
      int r = rr + i * 2;
      unsigned rec = srec[r];
      float v = 0.f;
      if (rec != 0xFFFFFFFFu) {
        int code = rec & 511;
        unsigned idx = rec >> 9;
        int s = idx & 127, d = (idx >> 7) & 127, g = idx >> 14;
        v = reluf(m1[((g << 7) + d) * Hh + c] + m2[((g << 7) + s) * Hh + c] +
                  me[code * Hh + c]);
      }
      ushort_t h, l;
      split2(v, h, l);
      MH[r][c] = h;
      ML[r][c] = l;
    }
  }
  __syncthreads();

  int lane = tid & 63, wid = tid >> 6;
  int lr = lane & 15, lg = lane >> 4;
  float b1v[8], b2v[8];
#pragma unroll
  for (int nf = 0; nf < 8; ++nf) {
    b1v[nf] = b_h1[16 * nf + lr];
    b2v[nf] = b_h2[16 * nf + lr];
  }
  int arow = 16 * wid + lr;
  bf16x8 ah[4], al[4];
  load_afrag(MH, ML, arow, lg, ah, al);
  f32x4 acc[8];
  wave_gemm(wt1h, wt1l, ah, al, lr, lg, acc);
  // T = relu(acc + b1) -> back into MH/ML (wave-private rows)
#pragma unroll
  for (int nf = 0; nf < 8; ++nf)
#pragma unroll
    for (int reg = 0; reg < 4; ++reg) {
      float t = reluf(acc[nf][reg] + b1v[nf]);
      int row = 16 * wid + lg * 4 + reg;
      int col = 16 * nf + lr;
      ushort_t h, l;
      split2(t, h, l);
      MH[row][col] = h;
      ML[row][col] = l;
    }
  __syncthreads();
  load_afrag(MH, ML, arow, lg, ah, al);
  wave_gemm(wt2h, wt2l, ah, al, lr, lg, acc);
  // park f32 result bits in MH/ML (wave-private rows)
#pragma unroll
  for (int nf = 0; nf < 8; ++nf)
#pragma unroll
    for (int reg = 0; reg < 4; ++reg) {
      int row = 16 * wid + lg * 4 + reg;
      int col = 16 * nf + lr;
      unsigned b = __float_as_uint(acc[nf][reg] + b2v[nf]);
      MH[row][col] = (ushort_t)(b >> 16);
      ML[row][col] = (ushort_t)(b & 0xFFFFu);
    }
  __syncthreads();
  // run-dedup scatter: rows sorted by (g,d) = rec>>16; one atomic per run per col
  {
    int c = tid & 127, half = tid >> 7;
    int rbeg = half * 32, rend = rbeg + 32;
    unsigned curkey = 0xFFFFu;
    float best = -3.0e38f;
    for (int r = rbeg; r < rend; ++r) {
      unsigned rec = srec[r];
      unsigned key = rec >> 16;   // g*128+d (<=0xFFF) or 0xFFFF if invalid
      if (key != curkey) {
        if (curkey != 0xFFFFu)
          atomicMax(aggk + (curkey << 7) + c, fkey(best));
        curkey = key;
        best = -3.0e38f;
      }
      if (key != 0xFFFFu) {
        unsigned b = ((unsigned)MH[r][c] << 16) | (unsigned)ML[r][c];
        best = fmaxf(best, __uint_as_float(b));
      }
    }
    if (curkey != 0xFFFFu)
      atomicMax(aggk + (curkey << 7) + c, fkey(best));
  }
}

// ---------------- hid update: relu([nf|hid|agg] @ [Wo1;Wo2] + b) via MFMA --------
__global__ __launch_bounds__(64) void k_out(const float* __restrict__ nf,
                                            const float* __restrict__ hid,
                                            const unsigned* __restrict__ aggk,
                                            const ushort_t* __restrict__ wo_h,
                                            const ushort_t* __restrict__ wo_l,
                                            const float* __restrict__ bo1,
                                            const float* __restrict__ bo2,
                                            float* __restrict__ hidn) {
  __shared__ ushort_t MH[16][136];
  __shared__ ushort_t ML[16][136];
  int tid = threadIdx.x;              // one wave
  int v0 = blockIdx.x * 16;
  int lr = tid & 15, lg = tid >> 4;
  f32x4 acc[8];
#pragma unroll
  for (int nfr = 0; nfr < 8; ++nfr) acc[nfr] = (f32x4){0.f, 0.f, 0.f, 0.f};

  for (int seg = 0; seg < 3; ++seg) {
    // stage 16x128 f32 segment as hi/lo bf16 (float4-vectorized)
#pragma unroll
    for (int i = 0; i < 8; ++i) {
      int idx = tid + i * 64;         // over 512 float4s
      int row = idx >> 5, c4 = idx & 31;
      float4 v;
      if (seg == 0)      v = ((const float4*)nf)[(v0 + row) * 32 + c4];
      else if (seg == 1) v = ((const float4*)hid)[(v0 + row) * 32 + c4];
      else {
        uint4 k4 = ((const uint4*)aggk)[(v0 + row) * 32 + c4];
        v.x = funkey(k4.x); v.y = funkey(k4.y); v.z = funkey(k4.z); v.w = funkey(k4.w);
      }
      us4 h4, l4;
      split2(v.x, h4.a, l4.a);
      split2(v.y, h4.b, l4.b);
      split2(v.z, h4.c, l4.c);
      split2(v.w, h4.d, l4.d);
      *(us4*)&MH[row][c4 * 4] = h4;
      *(us4*)&ML[row][c4 * 4] = l4;
    }
    __syncthreads();
    bf16x8 ah[4], al[4];
    load_afrag(MH, ML, lr, lg, ah, al);
#pragma unroll
    for (int nfr = 0; nfr < 8; ++nfr) {
      const ushort_t* bh_base = wo_h + (16 * nfr + lr) * 384 + seg * 128 + lg * 8;
      const ushort_t* bl_base = wo_l + (16 * nfr + lr) * 384 + seg * 128 + lg * 8;
#pragma unroll
      for (int kf = 0; kf < 4; ++kf) {
        bf16x8 bh = *(const bf16x8*)(bh_base + 32 * kf);
        bf16x8 bl = *(const bf16x8*)(bl_base + 32 * kf);
        acc[nfr] = __builtin_amdgcn_mfma_f32_16x16x32_bf16(ah[kf], bh, acc[nfr], 0, 0, 0);
        acc[nfr] = __builtin_amdgcn_mfma_f32_16x16x32_bf16(ah[kf], bl, acc[nfr], 0, 0, 0);
        acc[nfr] = __builtin_amdgcn_mfma_f32_16x16x32_bf16(al[kf], bh, acc[nfr], 0, 0, 0);
      }
    }
    __syncthreads();
  }
#pragma unroll
  for (int nfr = 0; nfr < 8; ++nfr) {
    int col = 16 * nfr + lr;
    float b = bo1[col] + bo2[col];
#pragma unroll
    for (int reg = 0; reg < 4; ++reg)
      hidn[(v0 + lg * 4 + reg) * Hh + col] = reluf(acc[nfr][reg] + b);
  }
}

// ---------------- readout head ----------------
__global__ __launch_bounds__(128) void k_head(const float* __restrict__ hid,
                                              const float* __restrict__ Wg1,
                                              const float* __restrict__ bg1,
                                              const float* __restrict__ Wg2,
                                              const float* __restrict__ bg2,
                                              float* __restrict__ out) {
  __shared__ float emb[Hh];
  __shared__ float tt[Hh];
  int g = blockIdx.x, j = threadIdx.x;
  float s = 0.f;
  for (int n = 0; n < Nn; ++n) s += hid[(g * Nn + n) * Hh + j];
  emb[j] = s * (1.f / Nn);
  __syncthreads();
  float a = bg1[j];
  for (int i = 0; i < Hh; ++i) a += emb[i] * Wg1[i * Hh + j];
  tt[j] = reluf(a);
  __syncthreads();
  if (j < 12) {
    float o = bg2[j];
    for (int i = 0; i < Hh; ++i) o += tt[i] * Wg2[i * 12 + j];
    out[g * 12 + j] = o;
  }
}

extern "C" void kernel_launch(void* const* d_in, const int* in_sizes, int n_in,
                              void* d_out, int out_size, void* d_ws, size_t ws_size,
                              hipStream_t stream) {
  const int* x = (const int*)d_in[0];
  const int* eidx32 = (const int*)d_in[1];
  const int* eattr = (const int*)d_in[2];
  const float* atom_tab = (const float*)d_in[4];
  const float* bond_tab = (const float*)d_in[5];
  const float* W_m1 = (const float*)d_in[6];
  const float* b_m1 = (const float*)d_in[7];
  const float* W_m2 = (const float*)d_in[8];
  const float* b_m2 = (const float*)d_in[9];
  const float* W_me = (const float*)d_in[10];
  const float* b_me = (const float*)d_in[11];
  const float* b_mg = (const float*)d_in[13];
  const float* W_h1 = (const float*)d_in[14];
  const float* b_h1 = (const float*)d_in[15];
  const float* W_h2 = (const float*)d_in[16];
  const float* b_h2 = (const float*)d_in[17];
  const float* W_o1 = (const float*)d_in[18];
  const float* b_o1 = (const float*)d_in[19];
  const float* W_o2 = (const float*)d_in[20];
  const float* b_o2 = (const float*)d_in[21];
  const float* Wg1 = (const float*)d_in[22];
  const float* bg1 = (const float*)d_in[23];
  const float* Wg2 = (const float*)d_in[24];
  const float* bg2 = (const float*)d_in[25];
  float* out = (float*)d_out;

  char* ws = (char*)d_ws;
  float* nf = (float*)(ws);                                 // 2MB
  float* hidA = (float*)(ws + (2u << 20));                  // 2MB
  float* hidB = (float*)(ws + (4u << 20));                  // 2MB
  float* m1 = (float*)(ws + (6u << 20));                    // 2MB
  float* m2 = (float*)(ws + (8u << 20));                    // 2MB
  unsigned* aggk = (unsigned*)(ws + (10u << 20));           // 2MB
  int* win = (int*)(ws + (12u << 20));                      // 2MB (dead after k_fill)
  ushort_t* wo = (ushort_t*)(ws + (12u << 20));             // 384KB (reuses win region)
  ushort_t* wt = (ushort_t*)(ws + (14u << 20));             // 256KB
  float* bf = (float*)(ws + (14u << 20) + (256u << 10));    // 256KB
  float* me = (float*)(ws + (14u << 20) + (512u << 10));    // 256KB
  unsigned* recs = (unsigned*)(ws + (14u << 20) + (768u << 10));  // 256KB
  int* blkcnt = (int*)(ws + (15u << 20));                   // 2KB
  int* blkoff = blkcnt + NSEG;                              // 2KB
  int* cnt = blkoff + NSEG;                                 // 4B
  int* eflag = cnt + 1;                                     // 4B

  hipMemsetAsync(win, 0xFF, GNN * sizeof(int), stream);
  k_detect<<<1, 128, 0, stream>>>(eidx32, eflag);
  k_node_encode<<<2048, 256, 0, stream>>>(x, atom_tab, nf, hidA);
  k_bond_fts<<<256, 256, 0, stream>>>(bond_tab, bf);
  k_scatter_win<<<256, 256, 0, stream>>>(eidx32, eflag, win);
  k_count<<<NSEG, 256, 0, stream>>>(win, blkcnt);
  k_scan<<<1, 512, 0, stream>>>(blkcnt, blkoff, cnt);
  k_fill<<<NSEG, 256, 0, stream>>>(win, eattr, blkoff, recs);
  k_wprep<<<256, 256, 0, stream>>>(W_h1, W_h2, wt);
  k_wprep_o<<<dim3(192, 2), 256, 0, stream>>>(W_o1, W_o2, wo);   // after k_fill: win dead

  float* hc = hidA;
  float* hn = hidB;
  for (int l = 0; l < 2; ++l) {
    const ushort_t* wt1h = wt + ((l * 2 + 0) * 2 + 0) * 16384;
    const ushort_t* wt1l = wt + ((l * 2 + 0) * 2 + 1) * 16384;
    const ushort_t* wt2h = wt + ((l * 2 + 1) * 2 + 0) * 16384;
    const ushort_t* wt2l = wt + ((l * 2 + 1) * 2 + 1) * 16384;
    const ushort_t* wo_h = wo + (l * 2 + 0) * 49152;
    const ushort_t* wo_l = wo + (l * 2 + 1) * 49152;
    k_me_init<<<256, 256, 0, stream>>>(bf, W_me + l * Hh * Hh, b_me + l * Hh,
                                       b_mg + l * Hh, me, aggk);
    k_m12<<<256, 256, 0, stream>>>(nf, hc, W_m1 + l * 2 * Hh * Hh, b_m1 + l * Hh,
                                   W_m2 + l * 2 * Hh * Hh, b_m2 + l * Hh, m1, m2);
    k_edge<<<1024, 256, 0, stream>>>(recs, cnt, m1, m2, me, wt1h, wt1l, wt2h, wt2l,
                                     b_h1 + l * Hh, b_h2 + l * Hh, aggk);
    k_out<<<256, 64, 0, stream>>>(nf, hc, aggk, wo_h, wo_l,
                                  b_o1 + l * Hh, b_o2 + l * Hh, hn);
    float* t = hc; hc = hn; hn = t;
  }
  k_head<<<32, 128, 0, stream>>>(hc, Wg1, bg1, Wg2, bg2, out);
}